// Round 3
// 448.422 us; speedup vs baseline: 1.0447x; 1.0447x over previous
//
#include <hip/hip_runtime.h>
#include <math.h>

// Problem constants (from reference)
#define BB 4
#define SS 8192
#define DD 2048
#define RKHS 1024
#define EMBD 128
#define NE 64
#define NTOK (BB * SS)          // 32768

typedef __attribute__((ext_vector_type(8))) _Float16 half8;
typedef __attribute__((ext_vector_type(4))) float f32x4;

// Workspace layout (no overlap; k_proj reads remb while writing Bsw):
//   Bsw   uint4[32768]   @ 0        512 KB   live K2->K3
//   remb  fp32[1024][64] @ 512K     256 KB   live K1->K2
//   c0    fp32[64]       @ 768K
#define BSW_OFF   0
#define REMB_OFF  (512 * 1024)
#define C0_OFF    (768 * 1024)

// ---------------------------------------------------------------------------
// K1: remb[r][e] = sum_d embeddings[e][d]*W_exp[r][d] + b_exp[r]  (fp64 acc)
// ---------------------------------------------------------------------------
__global__ __launch_bounds__(256) void k_emb(
    const float* __restrict__ emb, const float* __restrict__ W_exp,
    const float* __restrict__ b_exp, float* __restrict__ remb) {
  int u = threadIdx.x;
  int e = u & 63;
  int r = blockIdx.x * 4 + (u >> 6);
  const float* er = emb + (size_t)e * EMBD;
  const float* wr = W_exp + (size_t)r * EMBD;
  double a = (double)b_exp[r];
#pragma unroll 8
  for (int d4 = 0; d4 < EMBD / 4; ++d4) {
    float4 ev = *(const float4*)(er + d4 * 4);
    float4 wv = *(const float4*)(wr + d4 * 4);
    a += (double)ev.x * (double)wv.x;
    a += (double)ev.y * (double)wv.y;
    a += (double)ev.z * (double)wv.z;
    a += (double)ev.w * (double)wv.w;
  }
  remb[(size_t)r * NE + e] = (float)a;
}

// ---------------------------------------------------------------------------
// K2 (register-blocked fp64 VALU; NO MFMA — round-2's f64-MFMA fragment
// layout was unverified and produced scrambled C; pure VALU has no layout
// ambiguity): C[d][e] = sum_r W_hid[r][d]*remb[r][e], fp64 accumulation,
// with DIRECT emission of the MFMA B-fragment buffer Bsw (replaces k_swz).
//
// Grid: 257 blocks x 256 threads.
//   blocks 0..255: d-slab d0 = b*8 (8 d-rows), all 64 e.
//     Thread u: rq = u>>5 (8-way K-split), eg = (u>>1)&15 (4 e each),
//               dq = u&1 (4 d each).  acc[4][4] fp64, 16 FMA per
//               2 ds_read_b128 -> VALU-bound (vs baseline's 4 FMA per
//               b32+b128 -> LDS-bound, and only 129 blocks).
//     r-chunks of 64 staged in LDS (Wl 8 floats/row, Rl 64 floats/row);
//     thread's rows within chunk: rr = rq*8 + i, i=0..7.
//     8-way rq reduction through LDS (fp64), scale by 4096 -> Cf[8][64].
//     Emission (derived from the VERIFIED k_swz mapping): block b owns
//     kk = b>>2, q = b&3; for g=0..3, h=0..1, col=0..15:
//       Bsw[kk*512 + g*128 + h*64 + q*16 + col].v[j] =
//         (h ? lo : hi) of (Cf[j][g*16+col]),  j=0..7
//     since lane l = q*16+col of fragment (kk,g,h) holds
//     C16[kk*32 + (l>>4)*8 + j][g*16 + (l&15)] and kk*32+q*8 == d0.
//   block 256: c0[e] = sum_r b_hid[r]*remb[r][e]  (fp64, unchanged).
// ---------------------------------------------------------------------------
__global__ __launch_bounds__(256) void k_proj(
    const float* __restrict__ W_hid, const float* __restrict__ b_hid,
    const float* __restrict__ remb, uint4* __restrict__ Bsw,
    float* __restrict__ c0) {
  __shared__ float Wl[64][8];         //  2 KB
  __shared__ float Rl[64][64];        // 16 KB
  __shared__ double Sred[8][8][64];   // 32 KB  (rq partials)
  __shared__ float Cf[8][64];         //  2 KB  (scaled C slab)
  const int u = threadIdx.x;

  if (blockIdx.x == 256) {
    __shared__ double red[4][64];
    int e = u & 63, rq = u >> 6;
    double acc = 0.0;
#pragma unroll 8
    for (int i = 0; i < 256; ++i) {
      int r = rq * 256 + i;
      acc += (double)b_hid[r] * (double)remb[(size_t)r * NE + e];
    }
    red[rq][e] = acc;
    __syncthreads();
    if (u < 64) c0[u] = (float)(red[0][u] + red[1][u] + red[2][u] + red[3][u]);
    return;
  }

  const int d0 = blockIdx.x * 8;
  const int rq = u >> 5;        // 0..7
  const int eg = (u >> 1) & 15; // 0..15
  const int dq = u & 1;         // 0..1

  double acc[4][4];
#pragma unroll
  for (int a = 0; a < 4; ++a)
#pragma unroll
    for (int b = 0; b < 4; ++b) acc[a][b] = 0.0;

  for (int c = 0; c < 16; ++c) {
    const int r0 = c * 64;
    __syncthreads();
    // Wl: 64 rows x 8 floats = 128 float4; threads 0..127
    if (u < 128) {
      int row = u >> 1, d4 = u & 1;
      *(float4*)&Wl[row][d4 * 4] =
          *(const float4*)(W_hid + (size_t)(r0 + row) * DD + d0 + d4 * 4);
    }
    // Rl: 64 rows x 64 floats = 1024 float4; 4 per thread, coalesced rows
#pragma unroll
    for (int i = 0; i < 4; ++i) {
      int qq = i * 256 + u;
      int row = qq >> 4, c4 = qq & 15;
      *(float4*)&Rl[row][c4 * 4] =
          *(const float4*)(remb + (size_t)(r0 + row) * NE + c4 * 4);
    }
    __syncthreads();
#pragma unroll
    for (int i = 0; i < 8; ++i) {
      const int rr = rq * 8 + i;
      float4 wv = *(const float4*)&Wl[rr][dq * 4];
      float4 rv = *(const float4*)&Rl[rr][eg * 4];
      double w0 = (double)wv.x, w1 = (double)wv.y;
      double w2 = (double)wv.z, w3 = (double)wv.w;
      double r0v = (double)rv.x, r1v = (double)rv.y;
      double r2v = (double)rv.z, r3v = (double)rv.w;
      acc[0][0] += w0 * r0v; acc[0][1] += w0 * r1v;
      acc[0][2] += w0 * r2v; acc[0][3] += w0 * r3v;
      acc[1][0] += w1 * r0v; acc[1][1] += w1 * r1v;
      acc[1][2] += w1 * r2v; acc[1][3] += w1 * r3v;
      acc[2][0] += w2 * r0v; acc[2][1] += w2 * r1v;
      acc[2][2] += w2 * r2v; acc[2][3] += w2 * r3v;
      acc[3][0] += w3 * r0v; acc[3][1] += w3 * r1v;
      acc[3][2] += w3 * r2v; acc[3][3] += w3 * r3v;
    }
  }

  // park rq-partials in LDS
#pragma unroll
  for (int a = 0; a < 4; ++a)
#pragma unroll
    for (int b = 0; b < 4; ++b)
      Sred[rq][dq * 4 + a][eg * 4 + b] = acc[a][b];
  __syncthreads();

  // 8-way reduce -> Cf (512 outputs, 2 per thread)
#pragma unroll
  for (int t = 0; t < 2; ++t) {
    int o = t * 256 + u;
    int dl = o >> 6, e = o & 63;
    double s = 0.0;
#pragma unroll
    for (int k = 0; k < 8; ++k) s += Sred[k][dl][e];
    Cf[dl][e] = (float)(s * 4096.0);
  }
  __syncthreads();

  // direct Bsw emission (this block's 128 uint4)
  if (u < 128) {
    const int kk = blockIdx.x >> 2;
    const int q = blockIdx.x & 3;
    const int h = u >> 6;
    const int g = (u >> 4) & 3;
    const int col = u & 15;
    half8 v;
#pragma unroll
    for (int j = 0; j < 8; ++j) {
      float cv = Cf[j][g * 16 + col];
      _Float16 hi = (_Float16)cv;
      v[j] = h ? (_Float16)(cv - (float)hi) : hi;
    }
    Bsw[(size_t)kk * 512 + g * 128 + h * 64 + q * 16 + col] =
        __builtin_bit_cast(uint4, v);
  }
}

// ---------------------------------------------------------------------------
// K4: main router. 2048 blocks x 128 threads (2 waves; wave w owns K-half w).
// SCRATCH-FREE pipelined K-loop (unchanged from verified version).
// ---------------------------------------------------------------------------
#define LOADB(H0, L0, H1, L1, H2, L2, H3, L3, BQ)                          \
  H0 = (BQ)[0];   L0 = (BQ)[64];                                           \
  H1 = (BQ)[128]; L1 = (BQ)[192];                                          \
  H2 = (BQ)[256]; L2 = (BQ)[320];                                          \
  H3 = (BQ)[384]; L3 = (BQ)[448];

#define CVT1(I, X)                                                         \
  { float xx = (X); _Float16 hh = (_Float16)xx;                            \
    ah[I] = hh; al[I] = (_Float16)(xx - (float)hh); }

#define CONSUME(A0, A1, H0, L0, H1, L1, H2, L2, H3, L3)                    \
  {                                                                        \
    half8 ah, al;                                                          \
    CVT1(0, A0.x) CVT1(1, A0.y) CVT1(2, A0.z) CVT1(3, A0.w)                \
    CVT1(4, A1.x) CVT1(5, A1.y) CVT1(6, A1.z) CVT1(7, A1.w)                \
    const half8 bh0 = __builtin_bit_cast(half8, H0);                       \
    const half8 bL0 = __builtin_bit_cast(half8, L0);                       \
    const half8 bh1 = __builtin_bit_cast(half8, H1);                       \
    const half8 bL1 = __builtin_bit_cast(half8, L1);                       \
    const half8 bh2 = __builtin_bit_cast(half8, H2);                       \
    const half8 bL2 = __builtin_bit_cast(half8, L2);                       \
    const half8 bh3 = __builtin_bit_cast(half8, H3);                       \
    const half8 bL3 = __builtin_bit_cast(half8, L3);                       \
    acc0 = __builtin_amdgcn_mfma_f32_16x16x32_f16(ah, bh0, acc0, 0, 0, 0); \
    acc1 = __builtin_amdgcn_mfma_f32_16x16x32_f16(ah, bh1, acc1, 0, 0, 0); \
    acc2 = __builtin_amdgcn_mfma_f32_16x16x32_f16(ah, bh2, acc2, 0, 0, 0); \
    acc3 = __builtin_amdgcn_mfma_f32_16x16x32_f16(ah, bh3, acc3, 0, 0, 0); \
    acc0 = __builtin_amdgcn_mfma_f32_16x16x32_f16(al, bh0, acc0, 0, 0, 0); \
    acc1 = __builtin_amdgcn_mfma_f32_16x16x32_f16(al, bh1, acc1, 0, 0, 0); \
    acc2 = __builtin_amdgcn_mfma_f32_16x16x32_f16(al, bh2, acc2, 0, 0, 0); \
    acc3 = __builtin_amdgcn_mfma_f32_16x16x32_f16(al, bh3, acc3, 0, 0, 0); \
    acc0 = __builtin_amdgcn_mfma_f32_16x16x32_f16(ah, bL0, acc0, 0, 0, 0); \
    acc1 = __builtin_amdgcn_mfma_f32_16x16x32_f16(ah, bL1, acc1, 0, 0, 0); \
    acc2 = __builtin_amdgcn_mfma_f32_16x16x32_f16(ah, bL2, acc2, 0, 0, 0); \
    acc3 = __builtin_amdgcn_mfma_f32_16x16x32_f16(ah, bL3, acc3, 0, 0, 0); \
  }

__global__ __launch_bounds__(128, 3) void kernel_router(
    const float* __restrict__ in, const uint4* __restrict__ Bsw,
    const float* __restrict__ c0, float* __restrict__ out) {
  __shared__ float Lg[2][16][65];
  const int tid = threadIdx.x;
  const int l = tid & 63;
  const int w = tid >> 6;                     // K-half
  const size_t tok0 = (size_t)blockIdx.x * 16;
  const int q = (l >> 4) & 3;                 // quad
  const int col = l & 15;
  const float* arow = in + (tok0 + col) * DD + (size_t)w * (DD / 2) + q * 8;
  const uint4* bbase = Bsw + (size_t)w * 32 * 512 + l;

  f32x4 acc0 = {0.f, 0.f, 0.f, 0.f};
  f32x4 acc1 = {0.f, 0.f, 0.f, 0.f};
  f32x4 acc2 = {0.f, 0.f, 0.f, 0.f};
  f32x4 acc3 = {0.f, 0.f, 0.f, 0.f};

  uint4 xh0, xl0, xh1, xl1, xh2, xl2, xh3, xl3;
  uint4 yh0, yl0, yh1, yl1, yh2, yl2, yh3, yl3;
  float4 xa0, xa1, ya0, ya1;

  // preload X @ kk=0
  LOADB(xh0, xl0, xh1, xl1, xh2, xl2, xh3, xl3, bbase)
  xa0 = *(const float4*)(arow);
  xa1 = *(const float4*)(arow + 4);

  for (int kk = 0; kk < 32; kk += 2) {
    // load Y @ kk+1 (kk is even and <32, so kk+1 <= 31 always)
    {
      const uint4* bq = bbase + (size_t)(kk + 1) * 512;
      LOADB(yh0, yl0, yh1, yl1, yh2, yl2, yh3, yl3, bq)
      const float* ap = arow + (kk + 1) * 32;
      ya0 = *(const float4*)(ap);
      ya1 = *(const float4*)(ap + 4);
    }
    CONSUME(xa0, xa1, xh0, xl0, xh1, xl1, xh2, xl2, xh3, xl3)
    // load X @ min(kk+2, 31)  (last iter redundantly re-reads 31; harmless)
    {
      const int kn = (kk + 2 < 32) ? (kk + 2) : 31;
      const uint4* bq = bbase + (size_t)kn * 512;
      LOADB(xh0, xl0, xh1, xl1, xh2, xl2, xh3, xl3, bq)
      const float* ap = arow + kn * 32;
      xa0 = *(const float4*)(ap);
      xa1 = *(const float4*)(ap + 4);
    }
    CONSUME(ya0, ya1, yh0, yl0, yh1, yl1, yh2, yl2, yh3, yl3)
  }

  // epilogue: descale; wave 0 adds bias. C/D layout: col=lane&15, row=q*4+r.
  {
    const float inv = 1.0f / 4096.0f;
    const float base0 = w ? 0.f : c0[col];
    const float base1 = w ? 0.f : c0[16 + col];
    const float base2 = w ? 0.f : c0[32 + col];
    const float base3 = w ? 0.f : c0[48 + col];
#pragma unroll
    for (int r = 0; r < 4; ++r) {
      Lg[w][q * 4 + r][col]      = acc0[r] * inv + base0;
      Lg[w][q * 4 + r][16 + col] = acc1[r] * inv + base1;
      Lg[w][q * 4 + r][32 + col] = acc2[r] * inv + base2;
      Lg[w][q * 4 + r][48 + col] = acc3[r] * inv + base3;
    }
  }
  __syncthreads();

  if (tid < 16) {
    float m1 = Lg[0][tid][0] + Lg[1][tid][0];
    int i1 = 0;
#pragma unroll 8
    for (int e = 1; e < NE; ++e) {
      float v = Lg[0][tid][e] + Lg[1][tid][e];
      if (v > m1) { m1 = v; i1 = e; }
    }
    int i2 = (i1 == 0) ? 1 : 0;
    float m2 = Lg[0][tid][i2] + Lg[1][tid][i2];
#pragma unroll 8
    for (int e = 0; e < NE; ++e) {
      if (e == i1) continue;
      float v = Lg[0][tid][e] + Lg[1][tid][e];
      if (v > m2) { m2 = v; i2 = e; }
    }
    double ex = exp((double)m2 - (double)m1);
    double denom = 1.0 + ex;
    float rw1 = (float)(1.0 / denom);
    float rw2 = (float)(ex / denom);

    const size_t tg = tok0 + tid;
    *(float2*)(out + tg * 2) = make_float2((float)i1, (float)i2);
    *(float2*)(out + (size_t)NTOK * 2 + tg * 2) = make_float2(rw1, rw2);
  }
  // aux loss analytically constant: (K/E * 1/2) * E^2 = 64.0
  if (blockIdx.x == 0 && tid == 0) out[(size_t)NTOK * 4] = 64.0f;
}

// ---------------------------------------------------------------------------
extern "C" void kernel_launch(void* const* d_in, const int* in_sizes, int n_in,
                              void* d_out, int out_size, void* d_ws,
                              size_t ws_size, hipStream_t stream) {
  const float* input = (const float*)d_in[0];   // [4,8192,2048]
  const float* W_hid = (const float*)d_in[1];   // [1024,2048]
  const float* b_hid = (const float*)d_in[2];   // [1024]
  const float* W_exp = (const float*)d_in[3];   // [1024,128]
  const float* b_exp = (const float*)d_in[4];   // [1024]
  const float* emb = (const float*)d_in[5];     // [64,128]
  float* out = (float*)d_out;

  uint4* Bsw = (uint4*)((char*)d_ws + BSW_OFF);
  float* remb = (float*)((char*)d_ws + REMB_OFF);
  float* c0 = (float*)((char*)d_ws + C0_OFF);

  k_emb<<<RKHS / 4, 256, 0, stream>>>(emb, W_exp, b_exp, remb);
  k_proj<<<257, 256, 0, stream>>>(W_hid, b_hid, remb, Bsw, c0);
  kernel_router<<<NTOK / 16, 128, 0, stream>>>(input, Bsw, c0, out);
}